// Round 3
// baseline (1964.988 us; speedup 1.0000x reference)
//
#include <hip/hip_runtime.h>
#include <cstdint>
#include <cstddef>

typedef __attribute__((ext_vector_type(8))) short short8;
typedef __attribute__((ext_vector_type(4))) float f32x4;
typedef __attribute__((ext_vector_type(2))) float f32x2;
typedef __attribute__((ext_vector_type(2))) unsigned int u32x2;

#define SEQ 2048
#define NB  64
#define HID 256
#define M_TOTAL (SEQ*NB)   // 131072

__device__ __forceinline__ unsigned short f2bf(float x){
  unsigned u = __float_as_uint(x);
  u += 0x7fffu + ((u>>16)&1u);
  return (unsigned short)(u>>16);
}

// ---------- convert x fp32 -> bf16 (4 elems/thread) ----------
__global__ void k_convert_x(const float* __restrict__ x, unsigned short* __restrict__ xb){
  size_t i = (size_t)blockIdx.x*256 + threadIdx.x;
  f32x4 v = ((const f32x4*)x)[i];
  unsigned a0=f2bf(v[0]), a1=f2bf(v[1]), a2=f2bf(v[2]), a3=f2bf(v[3]);
  u32x2 o; o[0] = a0 | (a1<<16); o[1] = a2 | (a3<<16);
  ((u32x2*)xb)[i] = o;
}

// ---------- build transposed bf16 weights: BT[n][k] = W[k][n] ----------
__global__ void k_convert_w(const float* __restrict__ i2h, const float* __restrict__ h2o,
                            unsigned short* __restrict__ BT1, unsigned short* __restrict__ BT3){
  int k = blockIdx.x; int n = threadIdx.x;
  BT1[n*256+k] = f2bf(i2h[k*256+n]);
  BT3[n*256+k] = f2bf(h2o[k*256+n]);
}

// ---------- bf16 MFMA GEMM: C[M x 256] = A[M x 256] * B + bias ----------
__global__ __launch_bounds__(256) void k_gemm(
    const unsigned short* __restrict__ A, const unsigned short* __restrict__ BT,
    const float* __restrict__ bias, float* __restrict__ C)
{
  __shared__ __align__(16) unsigned short As[128*64];
  __shared__ __align__(16) unsigned short Bs[128*64];
  int tid = threadIdx.x;
  int bm = blockIdx.x, bn = blockIdx.y;
  int l = tid & 63, wv = tid >> 6;
  int wm = wv >> 1, wn = wv & 1;
  int lr = l & 15, lq = l >> 4;

  f32x4 acc[4][4];
  #pragma unroll
  for (int i=0;i<4;i++)
    #pragma unroll
    for (int j=0;j<4;j++) acc[i][j] = (f32x4)0.f;

  for (int kb=0; kb<4; ++kb){
    int k0 = kb*64;
    #pragma unroll
    for (int it=0; it<4; ++it){
      int f = it*256 + tid;
      int m = f >> 3;
      int kk = (f & 7) * 8;
      short8 va = *(const short8*)(A  + (size_t)(bm*128+m)*256 + k0 + kk);
      short8 vb = *(const short8*)(BT + (size_t)(bn*128+m)*256 + k0 + kk);
      *(short8*)(As + m*64 + kk) = va;
      *(short8*)(Bs + m*64 + kk) = vb;
    }
    __syncthreads();
    #pragma unroll
    for (int kt=0; kt<2; ++kt){
      short8 af[4], bfr[4];
      #pragma unroll
      for (int mt=0;mt<4;mt++){
        int row = wm*64 + mt*16 + lr;
        af[mt] = *(const short8*)(As + row*64 + kt*32 + lq*8);
      }
      #pragma unroll
      for (int nt=0;nt<4;nt++){
        int row = wn*64 + nt*16 + lr;
        bfr[nt] = *(const short8*)(Bs + row*64 + kt*32 + lq*8);
      }
      #pragma unroll
      for (int mt=0;mt<4;mt++)
        #pragma unroll
        for (int nt=0;nt<4;nt++)
          acc[mt][nt] = __builtin_amdgcn_mfma_f32_16x16x32_bf16(af[mt], bfr[nt], acc[mt][nt], 0, 0, 0);
    }
    __syncthreads();
  }
  #pragma unroll
  for (int nt=0;nt<4;nt++){
    int gn = bn*128 + wn*64 + nt*16 + lr;
    float bv = bias[gn];
    #pragma unroll
    for (int mt=0;mt<4;mt++){
      int gm = bm*128 + wm*64 + mt*16 + lq*4;
      #pragma unroll
      for (int r=0;r<4;r++)
        C[(size_t)(gm+r)*256 + gn] = acc[mt][nt][r] + bv;
    }
  }
}

// ---------- sequential scan: h_t = tanh(pre_t + h_{t-1} @ W_hh) ----------
// One block per batch, 1024 threads = 16 waves. Wave w: kc = w>>2 (k-chunk
// of 64), jq = w&3 (output quarter). Thread holds W_hh[kc*64..+63][j]
// (j = jq*64+lane) as 32 f32x2 k-pairs -> 32 v_pk_fma_f32 per step
// (halves the scalar-FMA issue floor that bound R2).
// Wave-PRIVATE h copy hbuf[w][64]: in phase h, each wave recomputes the
// h-slice it needs next step (4-way redundant, 1 expf/lane, all 16 waves
// busy) and writes its own copy -> no barrier between phase h and phase A.
// red[] double-buffered on t&1 -> exactly ONE __syncthreads per step.
__global__ __launch_bounds__(1024, 4) void k_scan(
    const float* __restrict__ i2h,     // (512,256); W_hh = rows [256,512)
    const float* __restrict__ h0,      // (64,256)
    const float* __restrict__ pre,     // (SEQ*NB,256) fp32 (lives in d_out)
    unsigned short* __restrict__ H)    // (SEQ*NB,256) bf16 out
{
  __shared__ __align__(16) float hbuf[16][64];     // wave-private h copies
  __shared__ __align__(16) float red[2][4][256];   // partials, dbuf on t&1
  int b    = blockIdx.x;
  int tid  = threadIdx.x;
  int lane = tid & 63;
  int w    = tid >> 6;       // wave 0..15
  int jq   = w & 3;          // output quarter (phase A)
  int kc   = w >> 2;         // k-chunk (phase A) and h-slice (phase h)
  int j    = jq*64 + lane;   // phase-A output column
  int jh   = kc*64 + lane;   // phase-h output element

  // weights: w2[i] = { W_hh[kc*64+2i][j], W_hh[kc*64+2i+1][j] }
  f32x2 w2[32];
  const float* Wp = i2h + (size_t)(256 + kc*64)*256 + j;
  #pragma unroll
  for (int i=0;i<32;i++){
    w2[i][0] = Wp[(size_t)(2*i  )*256];
    w2[i][1] = Wp[(size_t)(2*i+1)*256];
  }

  hbuf[w][lane] = h0[b*256 + jh];     // own-wave write; own-wave read later

  // per-wave pre pipeline, 2 steps deep (4-way redundant across kc-sharing
  // waves -> L1/L2 broadcast hits)
  float pv = pre[(size_t)b*256 + jh];
  float p1 = pre[((size_t)1*NB + b)*256 + jh];

  const float* hb = hbuf[w];

  for (int t=0; t<SEQ; ++t){
    // ---- phase A: partial matvec, k-paired pk_fma ----
    f32x2 a0 = (f32x2)0.f, a1 = (f32x2)0.f;
    const f32x4* hp = (const f32x4*)hb;   // wave-uniform -> broadcast b128
    #pragma unroll
    for (int i=0;i<16;i++){
      f32x4 h4 = hp[i];
      f32x2 hlo = __builtin_shufflevector(h4, h4, 0, 1);
      f32x2 hhi = __builtin_shufflevector(h4, h4, 2, 3);
      asm("v_pk_fma_f32 %0, %1, %2, %0" : "+v"(a0) : "v"(w2[2*i  ]), "v"(hlo));
      asm("v_pk_fma_f32 %0, %1, %2, %0" : "+v"(a1) : "v"(w2[2*i+1]), "v"(hhi));
    }
    f32x2 a = a0 + a1;
    red[t&1][kc][j] = a[0] + a[1];
    __syncthreads();                     // the ONLY barrier per step

    // ---- phase h: every wave recomputes its own h-slice (4x redundant) ----
    float p2 = (t+2 < SEQ) ? pre[((size_t)(t+2)*NB + b)*256 + jh] : 0.f;
    const float* rd = &red[t&1][0][jh];
    float s = pv + rd[0] + rd[256] + rd[512] + rd[768];
    float e = __expf(2.f*s);             // tanh(s) = 1 - 2/(e^(2s)+1)
    float h = 1.f - 2.f/(e+1.f);
    hbuf[w][lane] = h;                   // own copy; no barrier needed
    if (jq == 0)                         // one wave per kc stores H
      H[((size_t)t*NB + b)*256 + jh] = f2bf(h);
    pv = p1; p1 = p2;
  }
}

extern "C" void kernel_launch(void* const* d_in, const int* in_sizes, int n_in,
                              void* d_out, int out_size, void* d_ws, size_t ws_size,
                              hipStream_t stream) {
  const float* x     = (const float*)d_in[0];
  const float* h0    = (const float*)d_in[1];
  const float* i2h   = (const float*)d_in[2];
  const float* i2h_b = (const float*)d_in[3];
  const float* h2o   = (const float*)d_in[4];
  const float* h2o_b = (const float*)d_in[5];
  float* out = (float*)d_out;

  unsigned short* xb  = (unsigned short*)d_ws;
  unsigned short* BT1 = (unsigned short*)((char*)d_ws + (size_t)M_TOTAL*HID*2);
  unsigned short* BT3 = BT1 + 256*256;

  k_convert_x<<<M_TOTAL*HID/(256*4), 256, 0, stream>>>(x, xb);
  k_convert_w<<<256, 256, 0, stream>>>(i2h, h2o, BT1, BT3);

  dim3 g1(M_TOTAL/128, 2);
  k_gemm<<<g1, 256, 0, stream>>>(xb, BT1, i2h_b, out);
  k_scan<<<NB, 1024, 0, stream>>>(i2h, h0, out, xb);
  k_gemm<<<g1, 256, 0, stream>>>(xb, BT3, h2o_b, out);
}